// Round 10
// baseline (261.398 us; speedup 1.0000x reference)
//
#include <hip/hip_runtime.h>
#include <math.h>

#define N 8192
#define D 128
#define NC 256
#define NT 64                    // 128-wide tiles per dim
#define NBLK (NT * (NT + 1) / 2) // 2080

typedef __attribute__((ext_vector_type(8))) short bf8;   // 8 bf16 = 4 VGPRs
typedef __attribute__((ext_vector_type(4))) float f4;    // MFMA acc

__device__ __forceinline__ unsigned short bf16_rtne(float f) {
    unsigned u = __float_as_uint(f);
    u += 0x7FFF + ((u >> 16) & 1);
    return (unsigned short)(u >> 16);
}
__device__ __forceinline__ float bf16_tof(unsigned short h) {
    return __uint_as_float((unsigned)h << 16);
}

// async global->LDS DMA, 16 B/lane (global_load_lds_dwordx4). LDS side must
// be wave-uniform base + lane*16 (global side may scatter).
__device__ __forceinline__ void async_cp16(const void* g, void* l) {
    __builtin_amdgcn_global_load_lds(
        (const __attribute__((address_space(1))) unsigned*)g,
        (__attribute__((address_space(3))) unsigned*)l, 16, 0, 0);
}

// ---------------------------------------------------------------------------
// Kernel 1: normalize + 3-limb bf16 split (row-major), sq, histogram,
// best-pack init. n = x/||x||; n = h1+h2+h3 + O(2^-24).
// ---------------------------------------------------------------------------
__global__ __launch_bounds__(256) void prep_kernel(
    const float* __restrict__ x, const int* __restrict__ labels,
    short* __restrict__ H, float* __restrict__ sq, int* __restrict__ hist,
    unsigned long long* __restrict__ pos_pack,
    unsigned long long* __restrict__ neg_pack) {
    __shared__ float Xs[64 * 129];
    const int t = threadIdx.x;
    const int r0 = blockIdx.x * 64;

    {   // init best-packs: 128 blocks x 256 threads cover 8192
        const int g = blockIdx.x * 256 + t;
        if (g < N) { pos_pack[g] = 0ULL; neg_pack[g] = ~0ULL; }
    }

#pragma unroll
    for (int p = 0; p < 8; ++p) {
        const int lin = p * 256 + t;
        const int row = lin >> 5;
        const int c0 = (lin & 31) << 2;
        const float4 v = *(const float4*)(x + (size_t)(r0 + row) * D + c0);
        float* dst = &Xs[row * 129 + c0];
        dst[0] = v.x; dst[1] = v.y; dst[2] = v.z; dst[3] = v.w;
    }
    __syncthreads();

    const int r = t >> 2, q2 = t & 3;
    float* src = &Xs[r * 129 + q2 * 32];
    float s = 0.f;
#pragma unroll
    for (int i = 0; i < 32; ++i) s = fmaf(src[i], src[i], s);
    s += __shfl_xor(s, 1, 64);
    s += __shfl_xor(s, 2, 64);
    const float nrm = sqrtf(s);
    float t2 = 0.f;
#pragma unroll
    for (int i = 0; i < 32; ++i) {
        const float n = src[i] / nrm;
        src[i] = n;
        t2 = fmaf(n, n, t2);
    }
    t2 += __shfl_xor(t2, 1, 64);
    t2 += __shfl_xor(t2, 2, 64);
    if (q2 == 0) sq[r0 + r] = t2;

    const size_t gbase = (size_t)(r0 + r) * D + q2 * 32;
#pragma unroll
    for (int g = 0; g < 8; ++g) {
        short4 o1, o2, o3;
        short* p1 = (short*)&o1; short* p2 = (short*)&o2; short* p3 = (short*)&o3;
#pragma unroll
        for (int i = 0; i < 4; ++i) {
            const float n = src[g * 4 + i];
            const unsigned short h1 = bf16_rtne(n);
            const float r1 = n - bf16_tof(h1);
            const unsigned short h2 = bf16_rtne(r1);
            const float r2 = r1 - bf16_tof(h2);
            const unsigned short h3 = bf16_rtne(r2);
            p1[i] = (short)h1; p2[i] = (short)h2; p3[i] = (short)h3;
        }
        *(short4*)(H + gbase + g * 4)                     = o1;
        *(short4*)(H + (size_t)N * D + gbase + g * 4)     = o2;
        *(short4*)(H + (size_t)2 * N * D + gbase + g * 4) = o3;
    }

    if (t < 64) atomicAdd(&hist[labels[r0 + t]], 1);
}

// ---------------------------------------------------------------------------
// Kernel 2: symmetric 128x128-tile Gram via 3-limb bf16 MFMA. R10: B-panel
// only in LDS (24 KB -> more blocks/CU for phase overlap); A-fragments read
// straight from global (L2-resident H) between the barriers; d2 computed
// once in place; ct-outer/limb-inner to cap live VGPRs. Plain
// launch_bounds(256) — occupancy hints cause 64-reg spill (R4/R5).
// ---------------------------------------------------------------------------
__device__ __forceinline__ unsigned int fbits(float f) {
    union { float f; unsigned int u; } x; x.f = f; return x.u;
}
__device__ __forceinline__ unsigned long long pack_pos(float v, int j) {
    return ((unsigned long long)fbits(v) << 32) | (unsigned int)(8191 - j);
}
__device__ __forceinline__ unsigned long long pack_neg(float v, int j) {
    return ((unsigned long long)fbits(v) << 32) | (unsigned int)j;
}
__device__ __forceinline__ void red_max(float& v, int& j, int mask) {
    const float ov = __shfl_xor(v, mask, 64);
    const int   oj = __shfl_xor(j, mask, 64);
    if (ov > v || (ov == v && oj < j)) { v = ov; j = oj; }
}
__device__ __forceinline__ void red_min(float& v, int& j, int mask) {
    const float ov = __shfl_xor(v, mask, 64);
    const int   oj = __shfl_xor(j, mask, 64);
    if (ov < v || (ov == v && oj < j)) { v = ov; j = oj; }
}

__global__ __launch_bounds__(256) void miner_kernel(
    const short* __restrict__ H, const float* __restrict__ sq,
    const int* __restrict__ labels,
    unsigned long long* __restrict__ pos_pack,
    unsigned long long* __restrict__ neg_pack) {
    __shared__ __align__(16) short sB[3 * 128 * 32];  // 24 KB; reused as u64 scratch
    __shared__ float sqI[128], sqJ[128];
    __shared__ int   lbI[128], lbJ[128];

    const int t = threadIdx.x;
    const int w = t >> 6;       // wave id: rows w*32..w*32+31
    const int l = t & 63;
    const int quad = l >> 4;
    const int l16 = l & 15;

    // decode upper-triangular (bi, bj), bi <= bj, NT=64
    const int b = blockIdx.x;
    int bi = (int)((129.0f - sqrtf(16641.0f - 8.0f * (float)b)) * 0.5f);
    while (bi > 0 && (bi * NT - bi * (bi - 1) / 2) > b) --bi;
    while (((bi + 1) * NT - (bi + 1) * bi / 2) <= b) ++bi;
    const int bj = bi + (b - (bi * NT - bi * (bi - 1) / 2));
    const int I0 = bi * 128, J0 = bj * 128;
    const bool diag = (bi == bj);

    if (t < 128) { sqI[t] = sq[I0 + t]; lbI[t] = labels[I0 + t]; }
    else         { sqJ[t - 128] = sq[J0 + t - 128]; lbJ[t - 128] = labels[J0 + t - 128]; }

    // hoisted staging offsets (elements): B DMA, 6 x 16B per thread
    int bOff[6]; int bLds[6];
#pragma unroll
    for (int p = 0; p < 6; ++p) {
        const int c = p * 256 + t;          // 0..1535
        const int limb = c >> 9;
        const int cc   = c & 511;
        const int sample = cc >> 2;
        const int sub    = cc & 3;
        bOff[p] = limb * (N * D) + (J0 + sample) * D + sub * 8;
        bLds[p] = (limb * 128 + sample) * 32 + sub * 8;
    }
    // A-fragment per-lane offsets (element): row = I0 + w*32 + rt*16 + l16
    int aOff[2];
#pragma unroll
    for (int rt = 0; rt < 2; ++rt)
        aOff[rt] = (I0 + w * 32 + rt * 16 + l16) * D + quad * 8;

    f4 acc[2][8];
#pragma unroll
    for (int rt = 0; rt < 2; ++rt)
#pragma unroll
        for (int ct = 0; ct < 8; ++ct) acc[rt][ct] = (f4){0.f, 0.f, 0.f, 0.f};

    for (int q = 0; q < 4; ++q) {
        const int kc = q * 32;
        __syncthreads();                       // prev compute done -> sB free
#pragma unroll
        for (int p = 0; p < 6; ++p)
            async_cp16(H + (size_t)(bOff[p] + kc), sB + bLds[p]);
        // A-fragments from global (drained by the vmcnt(0) at next barrier)
        bf8 aF[3][2];
#pragma unroll
        for (int limb = 0; limb < 3; ++limb)
#pragma unroll
            for (int rt = 0; rt < 2; ++rt)
                aF[limb][rt] = *(const bf8*)
                    (H + (size_t)limb * (N * D) + (size_t)(aOff[rt] + kc));
        __syncthreads();

#pragma unroll
        for (int ct = 0; ct < 8; ++ct) {
            bf8 bF[3];
#pragma unroll
            for (int limb = 0; limb < 3; ++limb)
                bF[limb] = *(const bf8*)
                    &sB[(limb * 128 + ct * 16 + l16) * 32 + quad * 8];
#pragma unroll
            for (int lb = 0; lb < 3; ++lb)
#pragma unroll
                for (int la = 0; la + lb < 3; ++la)
#pragma unroll
                    for (int rt = 0; rt < 2; ++rt)
                        acc[rt][ct] = __builtin_amdgcn_mfma_f32_16x16x32_bf16(
                            aF[la][rt], bF[lb], acc[rt][ct], 0, 0, 0);
        }
    }

    // ---- epilogue: d2 in place, then scans ----
    float sjv[8]; int ljv[8];
#pragma unroll
    for (int ct = 0; ct < 8; ++ct) {
        sjv[ct] = sqJ[ct * 16 + l16];
        ljv[ct] = lbJ[ct * 16 + l16];
    }
    float siv[2][4]; int livv[2][4];
#pragma unroll
    for (int rt = 0; rt < 2; ++rt)
#pragma unroll
        for (int r = 0; r < 4; ++r) {
            const int lr = w * 32 + rt * 16 + quad * 4 + r;
            siv[rt][r] = sqI[lr];
            livv[rt][r] = lbI[lr];
        }
#pragma unroll
    for (int rt = 0; rt < 2; ++rt)
#pragma unroll
        for (int ct = 0; ct < 8; ++ct)
#pragma unroll
            for (int r = 0; r < 4; ++r)
                acc[rt][ct][r] =
                    fmaxf(siv[rt][r] + sjv[ct] - 2.0f * acc[rt][ct][r], 0.0f);

    // I-side: rows w*32+rt*16+quad*4+r; scan ct ascending, reduce l16 lanes
#pragma unroll
    for (int rt = 0; rt < 2; ++rt)
#pragma unroll
        for (int r = 0; r < 4; ++r) {
            const int grow = I0 + w * 32 + rt * 16 + quad * 4 + r;
            const int liv = livv[rt][r];
            float bpv = -1.0f, bnv = INFINITY; int bpj = 0, bnj = 0;
#pragma unroll
            for (int ct = 0; ct < 8; ++ct) {
                const float d2 = acc[rt][ct][r];
                const int col = J0 + ct * 16 + l16;
                const bool same = (liv == ljv[ct]);
                const float vp = (same && grow != col) ? d2 : 0.0f;
                if (vp > bpv) { bpv = vp; bpj = col; }
                const float vn = same ? INFINITY : d2;
                if (vn < bnv) { bnv = vn; bnj = col; }
            }
            red_max(bpv, bpj, 1); red_max(bpv, bpj, 2);
            red_max(bpv, bpj, 4); red_max(bpv, bpj, 8);
            red_min(bnv, bnj, 1); red_min(bnv, bnj, 2);
            red_min(bnv, bnj, 4); red_min(bnv, bnj, 8);
            if (l16 == 0) {
                atomicMax(&pos_pack[grow], pack_pos(bpv, bpj));
                atomicMin(&neg_pack[grow], pack_neg(bnv, bnj));
            }
        }

    // J-side (skip on diagonal): per-col best over the wave's 32 rows
    if (!diag) {
        float bpv[8], bnv[8]; int bpj[8], bnj[8];
#pragma unroll
        for (int ct = 0; ct < 8; ++ct) {
            bpv[ct] = -1.0f; bpj[ct] = 0; bnv[ct] = INFINITY; bnj[ct] = 0;
#pragma unroll
            for (int rt = 0; rt < 2; ++rt)
#pragma unroll
                for (int r = 0; r < 4; ++r) {
                    const float d2 = acc[rt][ct][r];
                    const int row = I0 + w * 32 + rt * 16 + quad * 4 + r;
                    const bool same = (livv[rt][r] == ljv[ct]);  // no self off-diag
                    const float vp = same ? d2 : 0.0f;
                    if (vp > bpv[ct]) { bpv[ct] = vp; bpj[ct] = row; }
                    const float vn = same ? INFINITY : d2;
                    if (vn < bnv[ct]) { bnv[ct] = vn; bnj[ct] = row; }
                }
#pragma unroll
            for (int m = 16; m < 64; m <<= 1) {
                red_max(bpv[ct], bpj[ct], m);
                red_min(bnv[ct], bnj[ct], m);
            }
        }
        unsigned long long* scr = (unsigned long long*)sB;  // 8 KB scratch
        __syncthreads();
        if (quad == 0) {
#pragma unroll
            for (int ct = 0; ct < 8; ++ct) {
                scr[w * 128 + ct * 16 + l16]       = pack_pos(bpv[ct], bpj[ct]);
                scr[512 + w * 128 + ct * 16 + l16] = pack_neg(bnv[ct], bnj[ct]);
            }
        }
        __syncthreads();
        if (t < 128) {
            unsigned long long mp = 0ULL, mn = ~0ULL;
#pragma unroll
            for (int ww = 0; ww < 4; ++ww) {
                const unsigned long long p = scr[ww * 128 + t];
                const unsigned long long qq = scr[512 + ww * 128 + t];
                if (p > mp) mp = p;
                if (qq < mn) mn = qq;
            }
            atomicMax(&pos_pack[J0 + t], mp);
            atomicMin(&neg_pack[J0 + t], mn);
        }
    }
}

// ---------------------------------------------------------------------------
// Kernel 3: finalize -> int32 outputs [anchor | pos | neg | keep]
// ---------------------------------------------------------------------------
__global__ void finalize_kernel(const unsigned long long* __restrict__ pos_pack,
                                const unsigned long long* __restrict__ neg_pack,
                                const int* __restrict__ labels,
                                const int* __restrict__ hist,
                                int* __restrict__ out) {
    const int r = blockIdx.x * 256 + threadIdx.x;
    out[r]         = r;
    out[N + r]     = 8191 - (int)(pos_pack[r] & 0xFFFFFFFFULL);
    out[2 * N + r] = (int)(neg_pack[r] & 0xFFFFFFFFULL);
    const int cnt = hist[labels[r]];
    out[3 * N + r] = (cnt >= 2 && cnt < N) ? 1 : 0;
}

extern "C" void kernel_launch(void* const* d_in, const int* in_sizes, int n_in,
                              void* d_out, int out_size, void* d_ws, size_t ws_size,
                              hipStream_t stream) {
    const float* x      = (const float*)d_in[0];
    const int*   labels = (const int*)d_in[1];
    int* out = (int*)d_out;

    short* H = (short*)d_ws;                                // 3*N*D bf16 = 6 MB
    float* sq = (float*)(H + (size_t)3 * N * D);            // N floats
    unsigned long long* pos_pack =
        (unsigned long long*)(sq + N);                      // N u64
    int* hist = (int*)(pos_pack + N);                       // NC ints
    unsigned long long* neg_pack =
        (unsigned long long*)(hist + NC);                   // N u64

    hipMemsetAsync(hist, 0, NC * 4, stream);
    prep_kernel<<<N / 64, 256, 0, stream>>>(x, labels, H, sq, hist,
                                            pos_pack, neg_pack);
    miner_kernel<<<NBLK, 256, 0, stream>>>(H, sq, labels, pos_pack, neg_pack);
    finalize_kernel<<<N / 256, 256, 0, stream>>>(pos_pack, neg_pack, labels, hist, out);
}

// Round 12
// 232.853 us; speedup vs baseline: 1.1226x; 1.1226x over previous
//
#include <hip/hip_runtime.h>
#include <math.h>

#define N 8192
#define D 128
#define NC 256
#define NT 64                    // 128-wide tiles per dim
#define NBLK (NT * (NT + 1) / 2) // 2080

typedef __attribute__((ext_vector_type(8))) short bf8;    // 8 bf16 = 4 VGPRs
typedef __attribute__((ext_vector_type(16))) float f16v;  // 32x32 MFMA acc

__device__ __forceinline__ unsigned short bf16_rtne(float f) {
    unsigned u = __float_as_uint(f);
    u += 0x7FFF + ((u >> 16) & 1);
    return (unsigned short)(u >> 16);
}
__device__ __forceinline__ float bf16_tof(unsigned short h) {
    return __uint_as_float((unsigned)h << 16);
}

// async global->LDS DMA, 16 B/lane (global_load_lds_dwordx4). LDS dst must be
// wave-uniform base + lane*16 — our staging map satisfies this (each wave
// covers 64 consecutive 16B chunks of one region).
__device__ __forceinline__ void async_cp16(const void* g, void* l) {
    __builtin_amdgcn_global_load_lds(
        (const __attribute__((address_space(1))) unsigned*)g,
        (__attribute__((address_space(3))) unsigned*)l, 16, 0, 0);
}

// ---------------------------------------------------------------------------
// Kernel 1: normalize + 3-limb bf16 split (row-major), sq, histogram,
// best-pack init. n = x/||x||; n = h1+h2+h3 + O(2^-24).
// ---------------------------------------------------------------------------
__global__ __launch_bounds__(256) void prep_kernel(
    const float* __restrict__ x, const int* __restrict__ labels,
    short* __restrict__ H, float* __restrict__ sq, int* __restrict__ hist,
    unsigned long long* __restrict__ pos_pack,
    unsigned long long* __restrict__ neg_pack) {
    __shared__ float Xs[64 * 129];
    const int t = threadIdx.x;
    const int r0 = blockIdx.x * 64;

    {   // init best-packs: 128 blocks x 256 threads cover 8192
        const int g = blockIdx.x * 256 + t;
        if (g < N) { pos_pack[g] = 0ULL; neg_pack[g] = ~0ULL; }
    }

#pragma unroll
    for (int p = 0; p < 8; ++p) {
        const int lin = p * 256 + t;
        const int row = lin >> 5;
        const int c0 = (lin & 31) << 2;
        const float4 v = *(const float4*)(x + (size_t)(r0 + row) * D + c0);
        float* dst = &Xs[row * 129 + c0];
        dst[0] = v.x; dst[1] = v.y; dst[2] = v.z; dst[3] = v.w;
    }
    __syncthreads();

    const int r = t >> 2, q2 = t & 3;
    float* src = &Xs[r * 129 + q2 * 32];
    float s = 0.f;
#pragma unroll
    for (int i = 0; i < 32; ++i) s = fmaf(src[i], src[i], s);
    s += __shfl_xor(s, 1, 64);
    s += __shfl_xor(s, 2, 64);
    const float nrm = sqrtf(s);
    float t2 = 0.f;
#pragma unroll
    for (int i = 0; i < 32; ++i) {
        const float n = src[i] / nrm;
        src[i] = n;
        t2 = fmaf(n, n, t2);
    }
    t2 += __shfl_xor(t2, 1, 64);
    t2 += __shfl_xor(t2, 2, 64);
    if (q2 == 0) sq[r0 + r] = t2;

    const size_t gbase = (size_t)(r0 + r) * D + q2 * 32;
#pragma unroll
    for (int g = 0; g < 8; ++g) {
        short4 o1, o2, o3;
        short* p1 = (short*)&o1; short* p2 = (short*)&o2; short* p3 = (short*)&o3;
#pragma unroll
        for (int i = 0; i < 4; ++i) {
            const float n = src[g * 4 + i];
            const unsigned short h1 = bf16_rtne(n);
            const float r1 = n - bf16_tof(h1);
            const unsigned short h2 = bf16_rtne(r1);
            const float r2 = r1 - bf16_tof(h2);
            const unsigned short h3 = bf16_rtne(r2);
            p1[i] = (short)h1; p2[i] = (short)h2; p3[i] = (short)h3;
        }
        *(short4*)(H + gbase + g * 4)                     = o1;
        *(short4*)(H + (size_t)N * D + gbase + g * 4)     = o2;
        *(short4*)(H + (size_t)2 * N * D + gbase + g * 4) = o3;
    }

    if (t < 64) atomicAdd(&hist[labels[r0 + t]], 1);
}

// ---------------------------------------------------------------------------
// Kernel 2: symmetric 128x128-tile Gram via 3-limb bf16 mfma_32x32x16.
// KC=16, double-buffered LDS (2 x 24 KB), ONE barrier per chunk: DMA for
// chunk q+1 overlaps MFMA of chunk q. R12 fix: staging decomposition now
// uses side=p/3, limb=p%3 (R11's `c & 767` was a bogus non-pow2 "mod" that
// skipped limb 1's staging entirely). A/B fragments gather identically from
// row-major limbs (HW k-permutation cancels); C/D map (HW-verified m74/m101):
// col=lane&31, row=(reg&3)+8*(reg>>2)+4*(lane>>5).
// Plain launch_bounds(256): occupancy hints cause 64-reg spill (R4/R5).
// ---------------------------------------------------------------------------
__device__ __forceinline__ unsigned int fbits(float f) {
    union { float f; unsigned int u; } x; x.f = f; return x.u;
}
__device__ __forceinline__ unsigned long long pack_pos(float v, int j) {
    return ((unsigned long long)fbits(v) << 32) | (unsigned int)(8191 - j);
}
__device__ __forceinline__ unsigned long long pack_neg(float v, int j) {
    return ((unsigned long long)fbits(v) << 32) | (unsigned int)j;
}
__device__ __forceinline__ void red_max(float& v, int& j, int mask) {
    const float ov = __shfl_xor(v, mask, 64);
    const int   oj = __shfl_xor(j, mask, 64);
    if (ov > v || (ov == v && oj < j)) { v = ov; j = oj; }
}
__device__ __forceinline__ void red_min(float& v, int& j, int mask) {
    const float ov = __shfl_xor(v, mask, 64);
    const int   oj = __shfl_xor(j, mask, 64);
    if (ov < v || (ov == v && oj < j)) { v = ov; j = oj; }
}

__global__ __launch_bounds__(256) void miner_kernel(
    const short* __restrict__ H, const float* __restrict__ sq,
    const int* __restrict__ labels,
    unsigned long long* __restrict__ pos_pack,
    unsigned long long* __restrict__ neg_pack) {
    // per buffer: A region [3 limb][2 kh][128 sample][8 elem] = 6144 shorts,
    // then B region same = 12288 shorts (24 KB); two buffers = 48 KB.
    __shared__ __align__(16) short sT[2][12288];
    __shared__ float sqI[128], sqJ[128];
    __shared__ int   lbI[128], lbJ[128];

    const int t = threadIdx.x;
    const int w = t >> 6;       // wave id: rows w*32..w*32+31
    const int l = t & 63;
    const int m = l & 31;       // row (A) / col (B) within 32-tile
    const int kh = l >> 5;      // k-half

    // decode upper-triangular (bi, bj), bi <= bj, NT=64
    const int b = blockIdx.x;
    int bi = (int)((129.0f - sqrtf(16641.0f - 8.0f * (float)b)) * 0.5f);
    while (bi > 0 && (bi * NT - bi * (bi - 1) / 2) > b) --bi;
    while (((bi + 1) * NT - (bi + 1) * bi / 2) <= b) ++bi;
    const int bj = bi + (b - (bi * NT - bi * (bi - 1) / 2));
    const int I0 = bi * 128, J0 = bj * 128;
    const bool diag = (bi == bj);

    if (t < 128) { sqI[t] = sq[I0 + t]; lbI[t] = labels[I0 + t]; }
    else         { sqJ[t - 128] = sq[J0 + t - 128]; lbJ[t - 128] = labels[J0 + t - 128]; }

    // staging offsets: 6 x 16B chunks per thread per k-chunk.
    // c = p*256 + t with t<256  =>  region index p (compile-time):
    // side = p/3 (0=A/I, 1=B/J), limb = p%3; within region: smp=t&127,
    // skh=t>>7. Wave lanes cover 64 consecutive 16B chunks -> DMA-legal.
    int gOff[6], lOff[6];   // element offset (sans kc), LDS short offset
#pragma unroll
    for (int p = 0; p < 6; ++p) {
        const int side = p / 3;
        const int limb = p % 3;
        const int smp  = t & 127;
        const int skh  = t >> 7;
        gOff[p] = limb * (N * D) + ((side ? J0 : I0) + smp) * D + skh * 8;
        lOff[p] = side * 6144 + ((limb * 2 + skh) * 128 + smp) * 8;
    }
    // fragment LDS short-offsets
    int aOffL[3], bOffL[3][4];
#pragma unroll
    for (int limb = 0; limb < 3; ++limb) {
        aOffL[limb] = ((limb * 2 + kh) * 128 + w * 32 + m) * 8;
#pragma unroll
        for (int ct = 0; ct < 4; ++ct)
            bOffL[limb][ct] = 6144 + ((limb * 2 + kh) * 128 + ct * 32 + m) * 8;
    }

    f16v acc[4];
#pragma unroll
    for (int ct = 0; ct < 4; ++ct)
#pragma unroll
        for (int e = 0; e < 16; ++e) acc[ct][e] = 0.f;

    // prologue stage chunk 0
#pragma unroll
    for (int p = 0; p < 6; ++p)
        async_cp16(H + (size_t)gOff[p], &sT[0][lOff[p]]);
    __syncthreads();

    for (int q = 0; q < 8; ++q) {
        if (q < 7) {
            const int kc = (q + 1) * 16;
            const int nb = (q + 1) & 1;
#pragma unroll
            for (int p = 0; p < 6; ++p)
                async_cp16(H + (size_t)(gOff[p] + kc), &sT[nb][lOff[p]]);
        }
        const short* base = sT[q & 1];
        bf8 aF[3];
#pragma unroll
        for (int limb = 0; limb < 3; ++limb)
            aF[limb] = *(const bf8*)&base[aOffL[limb]];
#pragma unroll
        for (int ct = 0; ct < 4; ++ct) {
            bf8 bF[3];
#pragma unroll
            for (int limb = 0; limb < 3; ++limb)
                bF[limb] = *(const bf8*)&base[bOffL[limb][ct]];
#pragma unroll
            for (int lb = 0; lb < 3; ++lb)
#pragma unroll
                for (int la = 0; la + lb < 3; ++la)
                    acc[ct] = __builtin_amdgcn_mfma_f32_32x32x16_bf16(
                        aF[la], bF[lb], acc[ct], 0, 0, 0);
        }
        __syncthreads();   // all reads of buf q done; DMA for q+1 drained
    }

    // ---- epilogue ----
    // rows held by this lane: lr(reg) = w*32 + 4*kh + (reg&3) + 8*(reg>>2)
    float sjv[4]; int ljv[4];
#pragma unroll
    for (int ct = 0; ct < 4; ++ct) {
        sjv[ct] = sqJ[ct * 32 + m];
        ljv[ct] = lbJ[ct * 32 + m];
    }
    float siv[16]; int liv[16]; int lrv[16];
#pragma unroll
    for (int reg = 0; reg < 16; ++reg) {
        const int lr = w * 32 + 4 * kh + (reg & 3) + 8 * (reg >> 2);
        lrv[reg] = lr; siv[reg] = sqI[lr]; liv[reg] = lbI[lr];
    }
    // d2 in place
#pragma unroll
    for (int ct = 0; ct < 4; ++ct)
#pragma unroll
        for (int reg = 0; reg < 16; ++reg)
            acc[ct][reg] = fmaxf(siv[reg] + sjv[ct] - 2.0f * acc[ct][reg], 0.0f);

    // I-side: per reg-row scan 4 cols, butterfly masks 1..16 (stays in the
    // 32-lane half that shares the row), commit from m==0 lanes.
#pragma unroll
    for (int reg = 0; reg < 16; ++reg) {
        const int grow = I0 + lrv[reg];
        const int liz = liv[reg];
        float bpv = -1.0f, bnv = INFINITY; int bpj = 0, bnj = 0;
#pragma unroll
        for (int ct = 0; ct < 4; ++ct) {
            const float d2 = acc[ct][reg];
            const int col = J0 + ct * 32 + m;
            const bool same = (liz == ljv[ct]);
            const float vp = (same && grow != col) ? d2 : 0.0f;
            if (vp > bpv) { bpv = vp; bpj = col; }
            const float vn = same ? INFINITY : d2;
            if (vn < bnv) { bnv = vn; bnj = col; }
        }
        red_max(bpv, bpj, 1); red_max(bpv, bpj, 2); red_max(bpv, bpj, 4);
        red_max(bpv, bpj, 8); red_max(bpv, bpj, 16);
        red_min(bnv, bnj, 1); red_min(bnv, bnj, 2); red_min(bnv, bnj, 4);
        red_min(bnv, bnj, 8); red_min(bnv, bnj, 16);
        if (m == 0) {
            atomicMax(&pos_pack[grow], pack_pos(bpv, bpj));
            atomicMin(&neg_pack[grow], pack_neg(bnv, bnj));
        }
    }

    // J-side (skip on diagonal): per col best over this lane's 16 rows,
    // merge halves (xor 32), cross-wave via LDS, one commit per col.
    if (!diag) {
        float bpv[4], bnv[4]; int bpj[4], bnj[4];
#pragma unroll
        for (int ct = 0; ct < 4; ++ct) {
            bpv[ct] = -1.0f; bpj[ct] = 0; bnv[ct] = INFINITY; bnj[ct] = 0;
#pragma unroll
            for (int reg = 0; reg < 16; ++reg) {
                const float d2 = acc[ct][reg];
                const int row = I0 + lrv[reg];
                const bool same = (liv[reg] == ljv[ct]);   // no self off-diag
                const float vp = same ? d2 : 0.0f;
                if (vp > bpv[ct]) { bpv[ct] = vp; bpj[ct] = row; }
                const float vn = same ? INFINITY : d2;
                if (vn < bnv[ct]) { bnv[ct] = vn; bnj[ct] = row; }
            }
            red_max(bpv[ct], bpj[ct], 32);
            red_min(bnv[ct], bnj[ct], 32);
        }
        unsigned long long* scr = (unsigned long long*)&sT[0][0];  // 8 KB
        __syncthreads();
        if (l < 32) {
#pragma unroll
            for (int ct = 0; ct < 4; ++ct) {
                scr[w * 128 + ct * 32 + m]       = pack_pos(bpv[ct], bpj[ct]);
                scr[512 + w * 128 + ct * 32 + m] = pack_neg(bnv[ct], bnj[ct]);
            }
        }
        __syncthreads();
        if (t < 128) {
            unsigned long long mp = 0ULL, mn = ~0ULL;
#pragma unroll
            for (int ww = 0; ww < 4; ++ww) {
                const unsigned long long p = scr[ww * 128 + t];
                const unsigned long long qq = scr[512 + ww * 128 + t];
                if (p > mp) mp = p;
                if (qq < mn) mn = qq;
            }
            atomicMax(&pos_pack[J0 + t], mp);
            atomicMin(&neg_pack[J0 + t], mn);
        }
    }
}

// ---------------------------------------------------------------------------
// Kernel 3: finalize -> int32 outputs [anchor | pos | neg | keep]
// ---------------------------------------------------------------------------
__global__ void finalize_kernel(const unsigned long long* __restrict__ pos_pack,
                                const unsigned long long* __restrict__ neg_pack,
                                const int* __restrict__ labels,
                                const int* __restrict__ hist,
                                int* __restrict__ out) {
    const int r = blockIdx.x * 256 + threadIdx.x;
    out[r]         = r;
    out[N + r]     = 8191 - (int)(pos_pack[r] & 0xFFFFFFFFULL);
    out[2 * N + r] = (int)(neg_pack[r] & 0xFFFFFFFFULL);
    const int cnt = hist[labels[r]];
    out[3 * N + r] = (cnt >= 2 && cnt < N) ? 1 : 0;
}

extern "C" void kernel_launch(void* const* d_in, const int* in_sizes, int n_in,
                              void* d_out, int out_size, void* d_ws, size_t ws_size,
                              hipStream_t stream) {
    const float* x      = (const float*)d_in[0];
    const int*   labels = (const int*)d_in[1];
    int* out = (int*)d_out;

    short* H = (short*)d_ws;                                // 3*N*D bf16 = 6 MB
    float* sq = (float*)(H + (size_t)3 * N * D);            // N floats
    unsigned long long* pos_pack =
        (unsigned long long*)(sq + N);                      // N u64
    int* hist = (int*)(pos_pack + N);                       // NC ints
    unsigned long long* neg_pack =
        (unsigned long long*)(hist + NC);                   // N u64

    hipMemsetAsync(hist, 0, NC * 4, stream);
    prep_kernel<<<N / 64, 256, 0, stream>>>(x, labels, H, sq, hist,
                                            pos_pack, neg_pack);
    miner_kernel<<<NBLK, 256, 0, stream>>>(H, sq, labels, pos_pack, neg_pack);
    finalize_kernel<<<N / 256, 256, 0, stream>>>(pos_pack, neg_pack, labels, hist, out);
}

// Round 13
// 174.717 us; speedup vs baseline: 1.4961x; 1.3327x over previous
//
#include <hip/hip_runtime.h>
#include <math.h>

#define N 8192
#define D 128
#define NT 64                    // 128-wide tiles per dim
#define NBLK (NT * (NT + 1) / 2) // 2080

typedef __attribute__((ext_vector_type(8))) short bf8;   // 8 bf16 = 4 VGPRs
typedef __attribute__((ext_vector_type(4))) float f4;    // MFMA acc

__device__ __forceinline__ unsigned short bf16_rtne(float f) {
    unsigned u = __float_as_uint(f);
    u += 0x7FFF + ((u >> 16) & 1);
    return (unsigned short)(u >> 16);
}
__device__ __forceinline__ float bf16_tof(unsigned short h) {
    return __uint_as_float((unsigned)h << 16);
}

__device__ __forceinline__ void async_cp16(const void* g, void* l) {
    __builtin_amdgcn_global_load_lds(
        (const __attribute__((address_space(1))) unsigned*)g,
        (__attribute__((address_space(3))) unsigned*)l, 16, 0, 0);
}

// ---------------------------------------------------------------------------
// Kernel 1: normalize + 3-limb bf16 split; 32 rows/block (256 blocks -> full
// CU spread). Also inits best-packs. No histogram (keep derived in finalize).
// ---------------------------------------------------------------------------
__global__ __launch_bounds__(256) void prep_kernel(
    const float* __restrict__ x, short* __restrict__ H,
    float* __restrict__ sq,
    unsigned long long* __restrict__ pos_pack,
    unsigned long long* __restrict__ neg_pack) {
    __shared__ float Xs[32 * 129];
    const int t = threadIdx.x;
    const int r0 = blockIdx.x * 32;

    if (t < 32) { pos_pack[r0 + t] = 0ULL; neg_pack[r0 + t] = ~0ULL; }

    // load 32x128 block (coalesced float4)
#pragma unroll
    for (int p = 0; p < 4; ++p) {
        const int lin = p * 256 + t;
        const int row = lin >> 5;
        const int c0 = (lin & 31) << 2;
        const float4 v = *(const float4*)(x + (size_t)(r0 + row) * D + c0);
        float* dst = &Xs[row * 129 + c0];
        dst[0] = v.x; dst[1] = v.y; dst[2] = v.z; dst[3] = v.w;
    }
    __syncthreads();

    // 8 threads/row, 16 elements each
    const int r = t >> 3, q8 = t & 7;
    float* src = &Xs[r * 129 + q8 * 16];
    float s = 0.f;
#pragma unroll
    for (int i = 0; i < 16; ++i) s = fmaf(src[i], src[i], s);
    s += __shfl_xor(s, 1, 64);
    s += __shfl_xor(s, 2, 64);
    s += __shfl_xor(s, 4, 64);
    const float nrm = sqrtf(s);
    float t2 = 0.f;
#pragma unroll
    for (int i = 0; i < 16; ++i) {
        const float n = src[i] / nrm;
        src[i] = n;
        t2 = fmaf(n, n, t2);
    }
    t2 += __shfl_xor(t2, 1, 64);
    t2 += __shfl_xor(t2, 2, 64);
    t2 += __shfl_xor(t2, 4, 64);
    if (q8 == 0) sq[r0 + r] = t2;

    const size_t gbase = (size_t)(r0 + r) * D + q8 * 16;
#pragma unroll
    for (int g = 0; g < 4; ++g) {
        short4 o1, o2, o3;
        short* p1 = (short*)&o1; short* p2 = (short*)&o2; short* p3 = (short*)&o3;
#pragma unroll
        for (int i = 0; i < 4; ++i) {
            const float n = src[g * 4 + i];
            const unsigned short h1 = bf16_rtne(n);
            const float r1 = n - bf16_tof(h1);
            const unsigned short h2 = bf16_rtne(r1);
            const float r2 = r1 - bf16_tof(h2);
            const unsigned short h3 = bf16_rtne(r2);
            p1[i] = (short)h1; p2[i] = (short)h2; p3[i] = (short)h3;
        }
        *(short4*)(H + gbase + g * 4)                     = o1;
        *(short4*)(H + (size_t)N * D + gbase + g * 4)     = o2;
        *(short4*)(H + (size_t)2 * N * D + gbase + g * 4) = o3;
    }
}

// ---------------------------------------------------------------------------
// Kernel 2: symmetric 128x128-tile Gram via 3-limb bf16 mfma_16x16x32.
// R13: LDS 40 KB (A limbs 0,1 + B limbs 0,1,2) -> 4 blocks/CU (16 waves);
// A-limb2 fragments read from global PRE-barrier (latency hidden by the
// staging barrier). sq/labels loaded into reused sT post-K-loop. Products
// (la+lb<=2) and layouts identical to the verified R9 kernel.
// Plain launch_bounds(256): occupancy hints pin VGPR=64 and spill (R4/R5).
// ---------------------------------------------------------------------------
__device__ __forceinline__ unsigned int fbits(float f) {
    union { float f; unsigned int u; } x; x.f = f; return x.u;
}
__device__ __forceinline__ unsigned long long pack_pos(float v, int j) {
    return ((unsigned long long)fbits(v) << 32) | (unsigned int)(8191 - j);
}
__device__ __forceinline__ unsigned long long pack_neg(float v, int j) {
    return ((unsigned long long)fbits(v) << 32) | (unsigned int)j;
}
__device__ __forceinline__ void red_max(float& v, int& j, int mask) {
    const float ov = __shfl_xor(v, mask, 64);
    const int   oj = __shfl_xor(j, mask, 64);
    if (ov > v || (ov == v && oj < j)) { v = ov; j = oj; }
}
__device__ __forceinline__ void red_min(float& v, int& j, int mask) {
    const float ov = __shfl_xor(v, mask, 64);
    const int   oj = __shfl_xor(j, mask, 64);
    if (ov < v || (ov == v && oj < j)) { v = ov; j = oj; }
}

__global__ __launch_bounds__(256) void miner_kernel(
    const short* __restrict__ H, const float* __restrict__ sq,
    const int* __restrict__ labels,
    unsigned long long* __restrict__ pos_pack,
    unsigned long long* __restrict__ neg_pack) {
    // A: [2 limb][128 smp][32 k] = 8192 shorts; B: [3 limb][128][32] = 12288.
    // Total 20480 shorts = 40960 B exactly -> 4 blocks/CU.
    __shared__ __align__(16) short sT[20480];

    const int t = threadIdx.x;
    const int w = t >> 6;       // wave id: rows w*32..w*32+31
    const int l = t & 63;
    const int quad = l >> 4;
    const int l16 = l & 15;

    // decode upper-triangular (bi, bj), bi <= bj, NT=64
    const int b = blockIdx.x;
    int bi = (int)((129.0f - sqrtf(16641.0f - 8.0f * (float)b)) * 0.5f);
    while (bi > 0 && (bi * NT - bi * (bi - 1) / 2) > b) --bi;
    while (((bi + 1) * NT - (bi + 1) * bi / 2) <= b) ++bi;
    const int bj = bi + (b - (bi * NT - bi * (bi - 1) / 2));
    const int I0 = bi * 128, J0 = bj * 128;
    const bool diag = (bi == bj);

    // staging offsets: 10 x 16B per thread per chunk.
    // p 0..3: A limbs 0,1 (limb=p>>1); p 4..9: B limbs 0,1,2 (limb=(p-4)>>1).
    // c2 = (p&1 within group)*256 + t; smp=c2>>2, sub=c2&3.
    int gOff[10], lOff[10];
#pragma unroll
    for (int p = 0; p < 10; ++p) {
        const int side = (p >= 4);
        const int pb   = side ? (p - 4) : p;
        const int limb = pb >> 1;
        const int c2   = (pb & 1) * 256 + t;
        const int smp  = c2 >> 2;
        const int sub  = c2 & 3;
        gOff[p] = limb * (N * D) + ((side ? J0 : I0) + smp) * D + sub * 8;
        lOff[p] = side * 8192 + ((limb * 128 + smp) * 32 + sub * 8);
    }
    // A-limb2 global element offsets (sans kc), per rt
    int aGoff[2];
#pragma unroll
    for (int rt = 0; rt < 2; ++rt)
        aGoff[rt] = 2 * (N * D) + (I0 + w * 32 + rt * 16 + l16) * D + quad * 8;

    f4 acc[2][8];
#pragma unroll
    for (int rt = 0; rt < 2; ++rt)
#pragma unroll
        for (int ct = 0; ct < 8; ++ct) acc[rt][ct] = (f4){0.f, 0.f, 0.f, 0.f};

    for (int q = 0; q < 4; ++q) {
        const int kc = q * 32;
        __syncthreads();                   // prev chunk's reads done
#pragma unroll
        for (int p = 0; p < 10; ++p)
            async_cp16(H + (size_t)(gOff[p] + kc), sT + lOff[p]);
        // A-limb2 fragments from global; latency hidden by the barrier drain
        bf8 aG[2];
#pragma unroll
        for (int rt = 0; rt < 2; ++rt)
            aG[rt] = *(const bf8*)(H + (size_t)(aGoff[rt] + kc));
        __syncthreads();                   // DMA + aG drained

        bf8 aF[2][2];
#pragma unroll
        for (int la = 0; la < 2; ++la)
#pragma unroll
            for (int rt = 0; rt < 2; ++rt)
                aF[la][rt] = *(const bf8*)
                    &sT[(la * 128 + w * 32 + rt * 16 + l16) * 32 + quad * 8];

#pragma unroll
        for (int ct = 0; ct < 8; ++ct) {
            bf8 bF[3];
#pragma unroll
            for (int lb = 0; lb < 3; ++lb)
                bF[lb] = *(const bf8*)
                    &sT[8192 + (lb * 128 + ct * 16 + l16) * 32 + quad * 8];
#pragma unroll
            for (int rt = 0; rt < 2; ++rt) {
                acc[rt][ct] = __builtin_amdgcn_mfma_f32_16x16x32_bf16(
                    aF[0][rt], bF[0], acc[rt][ct], 0, 0, 0);
                acc[rt][ct] = __builtin_amdgcn_mfma_f32_16x16x32_bf16(
                    aF[0][rt], bF[1], acc[rt][ct], 0, 0, 0);
                acc[rt][ct] = __builtin_amdgcn_mfma_f32_16x16x32_bf16(
                    aF[0][rt], bF[2], acc[rt][ct], 0, 0, 0);
                acc[rt][ct] = __builtin_amdgcn_mfma_f32_16x16x32_bf16(
                    aF[1][rt], bF[0], acc[rt][ct], 0, 0, 0);
                acc[rt][ct] = __builtin_amdgcn_mfma_f32_16x16x32_bf16(
                    aF[1][rt], bF[1], acc[rt][ct], 0, 0, 0);
                acc[rt][ct] = __builtin_amdgcn_mfma_f32_16x16x32_bf16(
                    aG[rt], bF[0], acc[rt][ct], 0, 0, 0);
            }
        }
    }

    // ---- load sq/labels into reused sT, then epilogue ----
    __syncthreads();
    float* sqI = (float*)sT;              // [0..128)
    float* sqJ = sqI + 128;               // [128..256)
    int*   lbI = (int*)(sqJ + 128);       // [256..384)
    int*   lbJ = lbI + 128;               // [384..512)  (2 KB total)
    if (t < 128) { sqI[t] = sq[I0 + t]; lbI[t] = labels[I0 + t]; }
    else { sqJ[t - 128] = sq[J0 + t - 128]; lbJ[t - 128] = labels[J0 + t - 128]; }
    __syncthreads();

    float sjv[8]; int ljv[8];
#pragma unroll
    for (int ct = 0; ct < 8; ++ct) {
        sjv[ct] = sqJ[ct * 16 + l16];
        ljv[ct] = lbJ[ct * 16 + l16];
    }
    // d2 in place
#pragma unroll
    for (int rt = 0; rt < 2; ++rt)
#pragma unroll
        for (int r = 0; r < 4; ++r) {
            const float si = sqI[w * 32 + rt * 16 + quad * 4 + r];
#pragma unroll
            for (int ct = 0; ct < 8; ++ct)
                acc[rt][ct][r] = fmaxf(si + sjv[ct] - 2.0f * acc[rt][ct][r], 0.0f);
        }

    // I-side (diag-specialized): per row scan 8 cols, butterfly l16 lanes.
#pragma unroll
    for (int rt = 0; rt < 2; ++rt)
#pragma unroll
        for (int r = 0; r < 4; ++r) {
            const int lr = w * 32 + rt * 16 + quad * 4 + r;
            const int grow = I0 + lr;
            const int liv = lbI[lr];
            float bpv = -1.0f, bnv = INFINITY; int bpj = 0, bnj = 0;
            if (diag) {
#pragma unroll
                for (int ct = 0; ct < 8; ++ct) {
                    const float d2 = acc[rt][ct][r];
                    const int col = J0 + ct * 16 + l16;
                    const bool same = (liv == ljv[ct]);
                    const float vp = (same && grow != col) ? d2 : 0.0f;
                    if (vp > bpv) { bpv = vp; bpj = col; }
                    const float vn = same ? INFINITY : d2;
                    if (vn < bnv) { bnv = vn; bnj = col; }
                }
            } else {
#pragma unroll
                for (int ct = 0; ct < 8; ++ct) {
                    const float d2 = acc[rt][ct][r];
                    const int col = J0 + ct * 16 + l16;
                    const bool same = (liv == ljv[ct]);
                    const float vp = same ? d2 : 0.0f;
                    if (vp > bpv) { bpv = vp; bpj = col; }
                    const float vn = same ? INFINITY : d2;
                    if (vn < bnv) { bnv = vn; bnj = col; }
                }
            }
            red_max(bpv, bpj, 1); red_max(bpv, bpj, 2);
            red_max(bpv, bpj, 4); red_max(bpv, bpj, 8);
            red_min(bnv, bnj, 1); red_min(bnv, bnj, 2);
            red_min(bnv, bnj, 4); red_min(bnv, bnj, 8);
            if (l16 == 0) {
                atomicMax(&pos_pack[grow], pack_pos(bpv, bpj));
                atomicMin(&neg_pack[grow], pack_neg(bnv, bnj));
            }
        }

    // J-side (skip on diagonal): per col best over this lane's 8 rows,
    // butterfly over quad (16,32), cross-wave merge via LDS, one commit/col.
    if (!diag) {
        float bpv[8], bnv[8]; int bpj[8], bnj[8];
#pragma unroll
        for (int ct = 0; ct < 8; ++ct) {
            bpv[ct] = -1.0f; bpj[ct] = 0; bnv[ct] = INFINITY; bnj[ct] = 0;
#pragma unroll
            for (int rt = 0; rt < 2; ++rt)
#pragma unroll
                for (int r = 0; r < 4; ++r) {
                    const int lr = w * 32 + rt * 16 + quad * 4 + r;
                    const float d2 = acc[rt][ct][r];
                    const int row = I0 + lr;
                    const bool same = (lbI[lr] == ljv[ct]);
                    const float vp = same ? d2 : 0.0f;
                    if (vp > bpv[ct]) { bpv[ct] = vp; bpj[ct] = row; }
                    const float vn = same ? INFINITY : d2;
                    if (vn < bnv[ct]) { bnv[ct] = vn; bnj[ct] = row; }
                }
#pragma unroll
            for (int m = 16; m < 64; m <<= 1) {
                red_max(bpv[ct], bpj[ct], m);
                red_min(bnv[ct], bnj[ct], m);
            }
        }
        unsigned long long* scr = (unsigned long long*)((char*)sT + 2048);
        __syncthreads();
        if (quad == 0) {
#pragma unroll
            for (int ct = 0; ct < 8; ++ct) {
                scr[w * 128 + ct * 16 + l16]       = pack_pos(bpv[ct], bpj[ct]);
                scr[512 + w * 128 + ct * 16 + l16] = pack_neg(bnv[ct], bnj[ct]);
            }
        }
        __syncthreads();
        if (t < 128) {
            unsigned long long mp = 0ULL, mn = ~0ULL;
#pragma unroll
            for (int ww = 0; ww < 4; ++ww) {
                const unsigned long long p = scr[ww * 128 + t];
                const unsigned long long qq = scr[512 + ww * 128 + t];
                if (p > mp) mp = p;
                if (qq < mn) mn = qq;
            }
            atomicMax(&pos_pack[J0 + t], mp);
            atomicMin(&neg_pack[J0 + t], mn);
        }
    }
}

// ---------------------------------------------------------------------------
// Kernel 3: finalize -> int32 outputs [anchor | pos | neg | keep].
// keep from pack sentinels: pos untouched (=0) means no positive committed;
// neg untouched (=~0) means no negative (both data-impossible here otherwise).
// ---------------------------------------------------------------------------
__global__ void finalize_kernel(const unsigned long long* __restrict__ pos_pack,
                                const unsigned long long* __restrict__ neg_pack,
                                int* __restrict__ out) {
    const int r = blockIdx.x * 256 + threadIdx.x;
    const unsigned long long pp = pos_pack[r];
    const unsigned long long np = neg_pack[r];
    out[r]         = r;
    out[N + r]     = 8191 - (int)(pp & 0xFFFFFFFFULL);
    out[2 * N + r] = (int)(np & 0xFFFFFFFFULL);
    out[3 * N + r] = (pp != 0ULL && np != ~0ULL) ? 1 : 0;
}

extern "C" void kernel_launch(void* const* d_in, const int* in_sizes, int n_in,
                              void* d_out, int out_size, void* d_ws, size_t ws_size,
                              hipStream_t stream) {
    const float* x      = (const float*)d_in[0];
    const int*   labels = (const int*)d_in[1];
    int* out = (int*)d_out;

    short* H = (short*)d_ws;                                // 3*N*D bf16 = 6 MB
    float* sq = (float*)(H + (size_t)3 * N * D);            // N floats
    unsigned long long* pos_pack =
        (unsigned long long*)(sq + N);                      // N u64
    unsigned long long* neg_pack = pos_pack + N;            // N u64

    prep_kernel<<<N / 32, 256, 0, stream>>>(x, H, sq, pos_pack, neg_pack);
    miner_kernel<<<NBLK, 256, 0, stream>>>(H, sq, labels, pos_pack, neg_pack);
    finalize_kernel<<<N / 256, 256, 0, stream>>>(pos_pack, neg_pack, out);
}